// Round 15
// baseline (101.062 us; speedup 1.0000x reference)
//
#include <hip/hip_runtime.h>
#include <stdint.h>

#define L_SEQ   2048
#define NBATCH  4
#define DM      512
#define DS      16
#define DR      32
#define NBDN    32768         // NBATCH*DM*DS chains
#define NCH     128           // chunks (= front blocks per batch)
#define CL      16            // chunk length = front block rows
#define LOG2E   1.4426950408889634f

// ws layout (float offsets)
#define WS_DX    0            // 4194304  packed (bf16 dt | bf16 xc) [b,l][d]
#define WS_XDBL  4194304      // 524288   x_dbl [row][64] (dt-raw | B | C) f32
#define WS_WXT   4718592      // 32768    WxT[k][j]
#define WS_WDTT  4751360      // 16384    WdtT[r][d]
#define WS_A2    4767744      // 8192     A2[d][n] = -exp(A_log)*log2e
#define WS_DTSUM 4775936      // 262144   dtsum[c][b*DM+d]
#define WS_S     5038080      // 4194304  S[c][chain]; scan2 rewrites in-place to Hin
// total 9232384 floats = 36.9 MB

__device__ __forceinline__ uint32_t bf16_rne_hi(float v) {   // bf16 in high 16 bits
    uint32_t u = __float_as_uint(v);
    u += 0x7FFF + ((u >> 16) & 1);
    return u & 0xFFFF0000u;
}
__device__ __forceinline__ float bf_lo(uint32_t u) { return __uint_as_float(u << 16); }
__device__ __forceinline__ float bf_hi(uint32_t u) { return __uint_as_float(u & 0xFFFF0000u); }

// ---------------- prep: weight transposes + A2 ----------------
__global__ void __launch_bounds__(256) k_prep(
        const float* __restrict__ Wx, const float* __restrict__ Wdt,
        const float* __restrict__ A_log, float* __restrict__ WxT,
        float* __restrict__ WdtT, float* __restrict__ A2) {
    int idx = blockIdx.x * 256 + threadIdx.x;
    if (idx < DM * 64) {                 // WxT[k][j] = Wx[j][k]
        int dd = idx >> 6, j = idx & 63;
        WxT[idx] = Wx[j * DM + dd];
    }
    if (idx < DR * DM) {                 // WdtT[r][d] = Wdt[d][r]
        int r = idx >> 9, dd = idx & 511;
        WdtT[idx] = Wdt[dd * DR + r];
    }
    if (idx < DM * DS)
        A2[idx] = -__expf(A_log[idx]) * LOG2E;
}

// ---------------- front32: conv + proj1 + proj2 + pack + IN-BLOCK chunk scan ----------------
// grid dim3(NCH, NBATCH); block = 256 threads = one chunk of 16 rows.
__global__ void __launch_bounds__(256) k_front(
        const float* __restrict__ x, const float* __restrict__ convw,
        const float* __restrict__ convb, const float* __restrict__ WxT,
        const float* __restrict__ WdtT, const float* __restrict__ dtb,
        const float* __restrict__ A2,
        uint32_t* __restrict__ dx, float* __restrict__ xdbl,
        float* __restrict__ S, float* __restrict__ dtsum) {
    __shared__ float xcs[CL][512];     // conv tile f32; aliased to packed u32 in phase C
    __shared__ float pt[8][CL][64];    // [ks][row][j] K-split partials
    __shared__ float xds[CL][64];      // reduced x_dbl rows (dt-raw | B | C)
    uint32_t* xcs_u32 = (uint32_t*)&xcs[0][0];

    int t  = threadIdx.x;
    int c  = blockIdx.x;
    int b  = blockIdx.y;
    int l0 = c * CL;
    int r0 = b * L_SEQ + l0;
    int dq = t & 127, rg = t >> 7;

    // ---- phase A: depthwise causal conv (K=4), float4 over d; 8 rows/thread ----
    {
        const float4* wp = (const float4*)convw;
        float4 w0 = wp[dq * 4 + 0], w1 = wp[dq * 4 + 1];
        float4 w2 = wp[dq * 4 + 2], w3 = wp[dq * 4 + 3];
        float4 bias = ((const float4*)convb)[dq];
        #pragma unroll
        for (int i = 0; i < 8; ++i) {
            int row = rg * 8 + i;
            int l   = l0 + row;
            const float* xr = x + ((size_t)(b * L_SEQ + l)) * DM + dq * 4;
            float4 acc = bias;
            float4 xv = *(const float4*)xr;
            acc.x = fmaf(xv.x, w0.w, acc.x); acc.y = fmaf(xv.y, w1.w, acc.y);
            acc.z = fmaf(xv.z, w2.w, acc.z); acc.w = fmaf(xv.w, w3.w, acc.w);
            if (l >= 1) {
                xv = *(const float4*)(xr - DM);
                acc.x = fmaf(xv.x, w0.z, acc.x); acc.y = fmaf(xv.y, w1.z, acc.y);
                acc.z = fmaf(xv.z, w2.z, acc.z); acc.w = fmaf(xv.w, w3.z, acc.w);
            }
            if (l >= 2) {
                xv = *(const float4*)(xr - 2 * DM);
                acc.x = fmaf(xv.x, w0.y, acc.x); acc.y = fmaf(xv.y, w1.y, acc.y);
                acc.z = fmaf(xv.z, w2.y, acc.z); acc.w = fmaf(xv.w, w3.y, acc.w);
            }
            if (l >= 3) {
                xv = *(const float4*)(xr - 3 * DM);
                acc.x = fmaf(xv.x, w0.x, acc.x); acc.y = fmaf(xv.y, w1.x, acc.y);
                acc.z = fmaf(xv.z, w2.x, acc.z); acc.w = fmaf(xv.w, w3.x, acc.w);
            }
            *(float4*)(&xcs[row][dq * 4]) = acc;
        }
    }
    __syncthreads();

    // ---- phase B: proj1 — thread owns 2 j-cols x 16 rows; 8 K-slices of 64 ----
    {
        int ks = t >> 5;                   // 0..7
        int jp = t & 31;                   // j = 2*jp, 2*jp+1
        int k0 = ks * 64;
        float accA[CL], accB[CL];
        #pragma unroll
        for (int ri = 0; ri < CL; ++ri) { accA[ri] = 0.f; accB[ri] = 0.f; }
        const float2* wp2 = (const float2*)WxT;    // [k][32 pairs]
        for (int k4 = 0; k4 < 16; ++k4) {
            float4 xr[CL];
            #pragma unroll
            for (int ri = 0; ri < CL; ++ri)
                xr[ri] = *(const float4*)(&xcs[ri][k0 + k4 * 4]);
            #pragma unroll
            for (int kk = 0; kk < 4; ++kk) {
                float2 w2 = wp2[(size_t)(k0 + k4 * 4 + kk) * 32 + jp];
                #pragma unroll
                for (int ri = 0; ri < CL; ++ri) {
                    float xv = ((const float*)&xr[ri])[kk];
                    accA[ri] = fmaf(xv, w2.x, accA[ri]);
                    accB[ri] = fmaf(xv, w2.y, accB[ri]);
                }
            }
        }
        #pragma unroll
        for (int ri = 0; ri < CL; ++ri)
            *(float2*)(&pt[ks][ri][jp * 2]) = make_float2(accA[ri], accB[ri]);
    }
    __syncthreads();

    // ---- reduce K-slices -> xds + global xdbl ----
    #pragma unroll
    for (int o = t; o < CL * 64; o += 256) {
        int row = o >> 6, j2 = o & 63;
        float s = ((pt[0][row][j2] + pt[1][row][j2]) + (pt[2][row][j2] + pt[3][row][j2]))
                + ((pt[4][row][j2] + pt[5][row][j2]) + (pt[6][row][j2] + pt[7][row][j2]));
        xds[row][j2] = s;
        xdbl[(size_t)(r0 + row) * 64 + j2] = s;
    }
    __syncthreads();

    // ---- phase C: proj2 + softplus + pack; write dx global + packed LDS (alias) ----
    {
        float4 bias = ((const float4*)dtb)[dq];
        float4 z[8];
        #pragma unroll
        for (int i = 0; i < 8; ++i) z[i] = bias;
        for (int r = 0; r < DR; ++r) {
            float4 w4 = *(const float4*)(WdtT + r * DM + dq * 4);
            #pragma unroll
            for (int i = 0; i < 8; ++i) {
                float xv = xds[rg * 8 + i][r];
                z[i].x = fmaf(xv, w4.x, z[i].x); z[i].y = fmaf(xv, w4.y, z[i].y);
                z[i].z = fmaf(xv, w4.z, z[i].z); z[i].w = fmaf(xv, w4.w, z[i].w);
            }
        }
        #pragma unroll
        for (int i = 0; i < 8; ++i) {
            int row = rg * 8 + i;
            float4 zi = z[i];
            float4 sp;
            sp.x = fmaxf(zi.x, 0.f) + log1pf(__expf(-fabsf(zi.x)));
            sp.y = fmaxf(zi.y, 0.f) + log1pf(__expf(-fabsf(zi.y)));
            sp.z = fmaxf(zi.z, 0.f) + log1pf(__expf(-fabsf(zi.z)));
            sp.w = fmaxf(zi.w, 0.f) + log1pf(__expf(-fabsf(zi.w)));
            uint4 pk;
            pk.x = bf16_rne_hi(sp.x) | (bf16_rne_hi(xcs[row][dq * 4 + 0]) >> 16);
            pk.y = bf16_rne_hi(sp.y) | (bf16_rne_hi(xcs[row][dq * 4 + 1]) >> 16);
            pk.z = bf16_rne_hi(sp.z) | (bf16_rne_hi(xcs[row][dq * 4 + 2]) >> 16);
            pk.w = bf16_rne_hi(sp.w) | (bf16_rne_hi(xcs[row][dq * 4 + 3]) >> 16);
            *(uint4*)(dx + ((size_t)(r0 + row)) * DM + dq * 4) = pk;
            *(uint4*)(&xcs_u32[row * 512 + dq * 4]) = pk;   // same slots this thread owns
        }
    }
    __syncthreads();

    // ---- phase D: in-block chunk-local scan (bit-identical math to old scan1) ----
    {
        int d0 = t * 2;                    // this thread: d0, d0+1
        float a2a[DS], a2b[DS];
        {
            const float4* apA = (const float4*)(A2 + (size_t)d0 * DS);
            const float4* apB = (const float4*)(A2 + (size_t)(d0 + 1) * DS);
            #pragma unroll
            for (int q = 0; q < 4; ++q) {
                float4 va = apA[q], vb = apB[q];
                a2a[q*4+0] = va.x; a2a[q*4+1] = va.y; a2a[q*4+2] = va.z; a2a[q*4+3] = va.w;
                a2b[q*4+0] = vb.x; a2b[q*4+1] = vb.y; a2b[q*4+2] = vb.z; a2b[q*4+3] = vb.w;
            }
        }
        float hA[DS], hB[DS];
        #pragma unroll
        for (int n = 0; n < DS; ++n) { hA[n] = 0.f; hB[n] = 0.f; }
        float dsA = 0.f, dsB = 0.f;

        for (int i = 0; i < CL; ++i) {
            uint2 w2 = *(const uint2*)(&xcs_u32[i * 512 + d0]);
            float dtA = bf_hi(w2.x), xvA = bf_lo(w2.x);
            float dtB = bf_hi(w2.y), xvB = bf_lo(w2.y);
            float uA = dtA * xvA, uB = dtB * xvB;
            dsA += dtA; dsB += dtB;
            #pragma unroll
            for (int q = 0; q < 4; ++q) {
                float4 B4 = *(const float4*)(&xds[i][DR + q * 4]);   // broadcast
                float Bs[4] = {B4.x, B4.y, B4.z, B4.w};
                #pragma unroll
                for (int k = 0; k < 4; ++k) {
                    int n = q * 4 + k;
                    float dA;
                    dA = exp2f(dtA * a2a[n]); hA[n] = fmaf(dA, hA[n], uA * Bs[k]);
                    dA = exp2f(dtB * a2b[n]); hB[n] = fmaf(dA, hB[n], uB * Bs[k]);
                }
            }
        }

        size_t sbase = (size_t)c * NBDN + ((size_t)(b * DM + d0)) * DS;
        float4* SpA = (float4*)(S + sbase);
        float4* SpB = (float4*)(S + sbase + DS);
        #pragma unroll
        for (int q = 0; q < 4; ++q) {
            SpA[q] = make_float4(hA[q*4+0], hA[q*4+1], hA[q*4+2], hA[q*4+3]);
            SpB[q] = make_float4(hB[q*4+0], hB[q*4+1], hB[q*4+2], hB[q*4+3]);
        }
        dtsum[c * (NBATCH * DM) + b * DM + d0]     = dsA;
        dtsum[c * (NBATCH * DM) + b * DM + d0 + 1] = dsB;
    }
}

// ---------------- scan2: cross-chunk prefix; P from dtsum telescope; in-place Hin ----------------
__global__ void __launch_bounds__(256) k_scan2(
        const float* __restrict__ dtsum, const float* __restrict__ A2,
        float* __restrict__ S) {
    int t  = blockIdx.x * 256 + threadIdx.x;       // 0..32767
    float a2 = A2[t & (DM * DS - 1)];
    int bd = t >> 4;                               // b*DM+d
    float H = 0.f;
    #pragma unroll 8
    for (int cc = 0; cc < NCH; ++cc) {
        float p = exp2f(a2 * dtsum[cc * (NBATCH * DM) + bd]);
        float s = S[(size_t)cc * NBDN + t];
        S[(size_t)cc * NBDN + t] = H;              // Hin for chunk cc
        H = fmaf(p, H, s);
    }
}

// ---------------- scan3: replay chunk from Hin, emit y ----------------
// grid dim3(8*NCH, NBATCH): x = db8(3) | c(7); y = b.
__global__ void __launch_bounds__(256) k_scan3(
        const uint32_t* __restrict__ dx, const float* __restrict__ xdbl,
        const float* __restrict__ A2, const float* __restrict__ Dvec,
        const float* __restrict__ Hin, float* __restrict__ out) {
    int t      = threadIdx.x;
    int lane   = t & 63;
    int wv     = t >> 6;
    int dlocal = lane & 15;
    int nq     = lane >> 4;
    int db8    = blockIdx.x & 7;
    int c      = blockIdx.x >> 3;
    int b      = blockIdx.y;
    int d      = (db8 * 4 + wv) * 16 + dlocal;
    int l0     = c * CL;

    float4 a2 = *(const float4*)(A2 + (size_t)d * DS + nq * 4);
    float Dv = Dvec[d];
    float4 hv = *(const float4*)(Hin + (size_t)c * NBDN + ((size_t)(b * DM + d)) * DS + nq * 4);
    float h0 = hv.x, h1 = hv.y, h2 = hv.z, h3 = hv.w;

    const uint32_t* dxp = dx + ((size_t)(b * L_SEQ + l0)) * DM + d;
    const float*    bp  = xdbl + ((size_t)(b * L_SEQ + l0)) * 64 + DR + nq * 4;
    float* op = out + ((size_t)(b * L_SEQ + l0)) * DM + d;

    #pragma unroll 8
    for (int i = 0; i < CL; ++i) {
        uint32_t v = dxp[(size_t)i * DM];
        float dt = bf_hi(v);
        float xv = bf_lo(v);
        float4 B4 = *(const float4*)(bp + (size_t)i * 64);
        float4 C4 = *(const float4*)(bp + (size_t)i * 64 + DS);
        float uu = dt * xv;
        float dA;
        dA = exp2f(dt * a2.x); h0 = fmaf(dA, h0, uu * B4.x);
        dA = exp2f(dt * a2.y); h1 = fmaf(dA, h1, uu * B4.y);
        dA = exp2f(dt * a2.z); h2 = fmaf(dA, h2, uu * B4.z);
        dA = exp2f(dt * a2.w); h3 = fmaf(dA, h3, uu * B4.w);
        float p = fmaf(h3, C4.w, fmaf(h2, C4.z, fmaf(h1, C4.y, h0 * C4.x)));
        p += __shfl_xor(p, 16);
        p += __shfl_xor(p, 32);
        if (nq == 0) op[(size_t)i * DM] = fmaf(xv, Dv, p);
    }
}

extern "C" void kernel_launch(void* const* d_in, const int* in_sizes, int n_in,
                              void* d_out, int out_size, void* d_ws, size_t ws_size,
                              hipStream_t stream) {
    const float* x      = (const float*)d_in[0];
    const float* A_log  = (const float*)d_in[1];
    const float* Dvec   = (const float*)d_in[2];
    const float* Wx     = (const float*)d_in[3];
    const float* Wdt    = (const float*)d_in[4];
    const float* dtb    = (const float*)d_in[5];
    const float* convw  = (const float*)d_in[6];
    const float* convb  = (const float*)d_in[7];
    float* out = (float*)d_out;
    float* wsf = (float*)d_ws;

    uint32_t* dx    = (uint32_t*)(wsf + WS_DX);
    float*    xdbl  = wsf + WS_XDBL;
    float*    WxT   = wsf + WS_WXT;
    float*    WdtT  = wsf + WS_WDTT;
    float*    A2    = wsf + WS_A2;
    float*    dtsum = wsf + WS_DTSUM;
    float*    S     = wsf + WS_S;

    k_prep<<<128, 256, 0, stream>>>(Wx, Wdt, A_log, WxT, WdtT, A2);
    k_front<<<dim3(NCH, NBATCH), 256, 0, stream>>>(x, convw, convb, WxT, WdtT, dtb,
                                                   A2, dx, xdbl, S, dtsum);
    k_scan2<<<128, 256, 0, stream>>>(dtsum, A2, S);
    k_scan3<<<dim3(8 * NCH, NBATCH), 256, 0, stream>>>(dx, xdbl, A2, Dvec, S, out);
}

// Round 16
// 100.248 us; speedup vs baseline: 1.0081x; 1.0081x over previous
//
#include <hip/hip_runtime.h>
#include <stdint.h>

#define L_SEQ   2048
#define NBATCH  4
#define DM      512
#define DS      16
#define DR      32
#define NBDN    32768         // NBATCH*DM*DS chains
#define NCH     64            // chunks
#define CL      32            // chunk length
#define LOG2E   1.4426950408889634f

// ws layout (float/uint offsets)
#define WS_DX    0            // 4194304  packed (bf16 dt | bf16 xc) [b,l][d]
#define WS_XDBL  4194304      // 524288   x_dbl [row][64] (dt-raw | B | C) f32
#define WS_WXT   4718592      // 32768    WxT[k][j]
#define WS_WDTT  4751360      // 16384    WdtT[r][d]
#define WS_A2    4767744      // 8192     A2[d][n] = -exp(A_log)*log2e
#define WS_DTSUM 4775936      // 131072   dtsum[c][b*DM+d]
#define WS_S     4907008      // 2097152  S[c][chain]; scan2 rewrites in-place to Hin
// total 7004160 floats = 28.0 MB

__device__ __forceinline__ uint32_t bf16_rne_hi(float v) {   // bf16 in high 16 bits
    uint32_t u = __float_as_uint(v);
    u += 0x7FFF + ((u >> 16) & 1);
    return u & 0xFFFF0000u;
}

// ---------------- prep: weight transposes + A2 ----------------
__global__ void __launch_bounds__(256) k_prep(
        const float* __restrict__ Wx, const float* __restrict__ Wdt,
        const float* __restrict__ A_log, float* __restrict__ WxT,
        float* __restrict__ WdtT, float* __restrict__ A2) {
    int idx = blockIdx.x * 256 + threadIdx.x;
    if (idx < DM * 64) {                 // WxT[k][j] = Wx[j][k]
        int dd = idx >> 6, j = idx & 63;
        WxT[idx] = Wx[j * DM + dd];
    }
    if (idx < DR * DM) {                 // WdtT[r][d] = Wdt[d][r]
        int r = idx >> 9, dd = idx & 511;
        WdtT[idx] = Wdt[dd * DR + r];
    }
    if (idx < DM * DS)
        A2[idx] = -__expf(A_log[idx]) * LOG2E;
}

// ---------------- front: conv + proj1 (rh2/ks4/j2) + proj2 + bf16 pack ----------------
// 1024 blocks x 256 threads; block = 8 consecutive rows. LDS 26KB -> 6 blocks/CU.
__global__ void __launch_bounds__(256) k_front(
        const float* __restrict__ x, const float* __restrict__ convw,
        const float* __restrict__ convb, const float* __restrict__ WxT,
        const float* __restrict__ WdtT, const float* __restrict__ dtb,
        uint32_t* __restrict__ dx, float* __restrict__ xdbl) {
    __shared__ float xcs[8][512];     // conv output tile
    __shared__ float pt[4][8][64];    // per-K-slice partials
    __shared__ float xds[8][64];      // reduced x_dbl rows
    int t  = threadIdx.x;
    int r0 = blockIdx.x * 8;
    int b  = r0 >> 11, l0 = r0 & (L_SEQ - 1);
    int dq = t & 127, half = t >> 7;

    // ---- phase A: depthwise causal conv (K=4), float4 over d ----
    {
        const float4* wp = (const float4*)convw;
        float4 w0 = wp[dq * 4 + 0], w1 = wp[dq * 4 + 1];
        float4 w2 = wp[dq * 4 + 2], w3 = wp[dq * 4 + 3];
        float4 bias = ((const float4*)convb)[dq];
        #pragma unroll
        for (int i = 0; i < 4; ++i) {
            int row = half * 4 + i;
            int l   = l0 + row;
            const float* xr = x + ((size_t)(b * L_SEQ + l)) * DM + dq * 4;
            float4 acc = bias;
            float4 xv = *(const float4*)xr;
            acc.x = fmaf(xv.x, w0.w, acc.x); acc.y = fmaf(xv.y, w1.w, acc.y);
            acc.z = fmaf(xv.z, w2.w, acc.z); acc.w = fmaf(xv.w, w3.w, acc.w);
            if (l >= 1) {
                xv = *(const float4*)(xr - DM);
                acc.x = fmaf(xv.x, w0.z, acc.x); acc.y = fmaf(xv.y, w1.z, acc.y);
                acc.z = fmaf(xv.z, w2.z, acc.z); acc.w = fmaf(xv.w, w3.z, acc.w);
            }
            if (l >= 2) {
                xv = *(const float4*)(xr - 2 * DM);
                acc.x = fmaf(xv.x, w0.y, acc.x); acc.y = fmaf(xv.y, w1.y, acc.y);
                acc.z = fmaf(xv.z, w2.y, acc.z); acc.w = fmaf(xv.w, w3.y, acc.w);
            }
            if (l >= 3) {
                xv = *(const float4*)(xr - 3 * DM);
                acc.x = fmaf(xv.x, w0.x, acc.x); acc.y = fmaf(xv.y, w1.x, acc.y);
                acc.z = fmaf(xv.z, w2.x, acc.z); acc.w = fmaf(xv.w, w3.x, acc.w);
            }
            *(float4*)(&xcs[row][dq * 4]) = acc;
        }
    }
    __syncthreads();

    // ---- phase B: proj1 — thread = (rowhalf, K-slice, j-pair); half the DS reads of R8 ----
    {
        int rh = t >> 7;                   // 0..1 -> rows rh*4 .. rh*4+3
        int ks = (t >> 5) & 3;             // 0..3 -> K-slice [ks*128, ks*128+128)
        int jp = t & 31;                   // j = 2*jp, 2*jp+1
        int k0 = ks * 128;
        float accA[4] = {0.f, 0.f, 0.f, 0.f};
        float accB[4] = {0.f, 0.f, 0.f, 0.f};
        const float2* wp2 = (const float2*)WxT;    // [k][32 j-pairs]
        for (int k4 = 0; k4 < 32; ++k4) {
            float4 xr[4];
            #pragma unroll
            for (int ri = 0; ri < 4; ++ri)
                xr[ri] = *(const float4*)(&xcs[rh * 4 + ri][k0 + k4 * 4]);
            #pragma unroll
            for (int kk = 0; kk < 4; ++kk) {
                float2 w2 = wp2[(size_t)(k0 + k4 * 4 + kk) * 32 + jp];
                #pragma unroll
                for (int ri = 0; ri < 4; ++ri) {
                    float xv = ((const float*)&xr[ri])[kk];
                    accA[ri] = fmaf(xv, w2.x, accA[ri]);
                    accB[ri] = fmaf(xv, w2.y, accB[ri]);
                }
            }
        }
        #pragma unroll
        for (int ri = 0; ri < 4; ++ri)
            *(float2*)(&pt[ks][rh * 4 + ri][jp * 2]) = make_float2(accA[ri], accB[ri]);
    }
    __syncthreads();

    // ---- reduce the 4 K-slices -> xds + global xdbl (same order as R8) ----
    #pragma unroll
    for (int o = t; o < 512; o += 256) {
        int row = o >> 6, j2 = o & 63;
        float s = (pt[0][row][j2] + pt[1][row][j2])
                + (pt[2][row][j2] + pt[3][row][j2]);
        xds[row][j2] = s;
        xdbl[(size_t)(r0 + row) * 64 + j2] = s;
    }
    __syncthreads();

    // ---- phase C: proj2 + softplus + pack (dt|xc) bf16 ----
    {
        float4 bias = ((const float4*)dtb)[dq];
        float4 z0 = bias, z1 = bias, z2 = bias, z3 = bias;
        for (int r = 0; r < DR; ++r) {
            float4 w4 = *(const float4*)(WdtT + r * DM + dq * 4);
            float x0 = xds[half * 4 + 0][r];
            float x1 = xds[half * 4 + 1][r];
            float x2 = xds[half * 4 + 2][r];
            float x3 = xds[half * 4 + 3][r];
            z0.x = fmaf(x0, w4.x, z0.x); z0.y = fmaf(x0, w4.y, z0.y);
            z0.z = fmaf(x0, w4.z, z0.z); z0.w = fmaf(x0, w4.w, z0.w);
            z1.x = fmaf(x1, w4.x, z1.x); z1.y = fmaf(x1, w4.y, z1.y);
            z1.z = fmaf(x1, w4.z, z1.z); z1.w = fmaf(x1, w4.w, z1.w);
            z2.x = fmaf(x2, w4.x, z2.x); z2.y = fmaf(x2, w4.y, z2.y);
            z2.z = fmaf(x2, w4.z, z2.z); z2.w = fmaf(x2, w4.w, z2.w);
            z3.x = fmaf(x3, w4.x, z3.x); z3.y = fmaf(x3, w4.y, z3.y);
            z3.z = fmaf(x3, w4.z, z3.z); z3.w = fmaf(x3, w4.w, z3.w);
        }
        float4 zz[4] = {z0, z1, z2, z3};
        #pragma unroll
        for (int i = 0; i < 4; ++i) {
            int row = half * 4 + i;
            float4 zi = zz[i];
            float4 sp;
            sp.x = fmaxf(zi.x, 0.f) + log1pf(__expf(-fabsf(zi.x)));
            sp.y = fmaxf(zi.y, 0.f) + log1pf(__expf(-fabsf(zi.y)));
            sp.z = fmaxf(zi.z, 0.f) + log1pf(__expf(-fabsf(zi.z)));
            sp.w = fmaxf(zi.w, 0.f) + log1pf(__expf(-fabsf(zi.w)));
            uint4 pk;
            pk.x = bf16_rne_hi(sp.x) | (bf16_rne_hi(xcs[row][dq * 4 + 0]) >> 16);
            pk.y = bf16_rne_hi(sp.y) | (bf16_rne_hi(xcs[row][dq * 4 + 1]) >> 16);
            pk.z = bf16_rne_hi(sp.z) | (bf16_rne_hi(xcs[row][dq * 4 + 2]) >> 16);
            pk.w = bf16_rne_hi(sp.w) | (bf16_rne_hi(xcs[row][dq * 4 + 3]) >> 16);
            *(uint4*)(dx + ((size_t)(b * L_SEQ + l0 + row)) * DM + dq * 4) = pk;
        }
    }
}

// ---------------- scan1: per-chunk local scan; lane = (dlocal, nq), 4 states ----------------
__global__ void __launch_bounds__(256) k_scan1(
        const uint32_t* __restrict__ dx, const float* __restrict__ xdbl,
        const float* __restrict__ A2, float* __restrict__ S,
        float* __restrict__ dtsum) {
    int t      = threadIdx.x;
    int lane   = t & 63;
    int wv     = t >> 6;
    int dlocal = lane & 15;
    int nq     = lane >> 4;
    int db8    = blockIdx.x & 7;
    int c      = blockIdx.x >> 3;
    int b      = blockIdx.y;
    int d      = (db8 * 4 + wv) * 16 + dlocal;
    int l0     = c * CL;

    float4 a2 = *(const float4*)(A2 + (size_t)d * DS + nq * 4);
    float h0 = 0.f, h1 = 0.f, h2 = 0.f, h3 = 0.f;
    float dsum = 0.f;
    const uint32_t* dxp = dx + ((size_t)(b * L_SEQ + l0)) * DM + d;
    const float*    bp  = xdbl + ((size_t)(b * L_SEQ + l0)) * 64 + DR + nq * 4;

    #pragma unroll 4
    for (int i = 0; i < CL; ++i) {
        uint32_t v = dxp[(size_t)i * DM];
        float dt = __uint_as_float(v & 0xFFFF0000u);
        float xv = __uint_as_float(v << 16);
        float4 B4 = *(const float4*)(bp + (size_t)i * 64);
        float u = dt * xv;
        dsum += dt;
        float dA;
        dA = exp2f(dt * a2.x); h0 = fmaf(dA, h0, u * B4.x);
        dA = exp2f(dt * a2.y); h1 = fmaf(dA, h1, u * B4.y);
        dA = exp2f(dt * a2.z); h2 = fmaf(dA, h2, u * B4.z);
        dA = exp2f(dt * a2.w); h3 = fmaf(dA, h3, u * B4.w);
    }

    float4 sv; sv.x = h0; sv.y = h1; sv.z = h2; sv.w = h3;
    *(float4*)(S + (size_t)c * NBDN + ((size_t)(b * DM + d)) * DS + nq * 4) = sv;
    if (nq == 0)
        dtsum[c * (NBATCH * DM) + b * DM + d] = dsum;
}

// ---------------- scan2: cross-chunk prefix; P from dtsum telescope; in-place Hin ----------------
__global__ void __launch_bounds__(256) k_scan2(
        const float* __restrict__ dtsum, const float* __restrict__ A2,
        float* __restrict__ S) {
    int t  = blockIdx.x * 256 + threadIdx.x;       // 0..32767
    float a2 = A2[t & (DM * DS - 1)];
    int bd = t >> 4;                               // b*DM+d
    float H = 0.f;
    #pragma unroll 8
    for (int cc = 0; cc < NCH; ++cc) {
        float p = exp2f(a2 * dtsum[cc * (NBATCH * DM) + bd]);
        float s = S[(size_t)cc * NBDN + t];
        S[(size_t)cc * NBDN + t] = H;              // Hin for chunk cc
        H = fmaf(p, H, s);
    }
}

// ---------------- scan3: replay chunk from Hin, emit y ----------------
__global__ void __launch_bounds__(256) k_scan3(
        const uint32_t* __restrict__ dx, const float* __restrict__ xdbl,
        const float* __restrict__ A2, const float* __restrict__ Dvec,
        const float* __restrict__ Hin, float* __restrict__ out) {
    int t      = threadIdx.x;
    int lane   = t & 63;
    int wv     = t >> 6;
    int dlocal = lane & 15;
    int nq     = lane >> 4;
    int db8    = blockIdx.x & 7;
    int c      = blockIdx.x >> 3;
    int b      = blockIdx.y;
    int d      = (db8 * 4 + wv) * 16 + dlocal;
    int l0     = c * CL;

    float4 a2 = *(const float4*)(A2 + (size_t)d * DS + nq * 4);
    float Dv = Dvec[d];
    float4 hv = *(const float4*)(Hin + (size_t)c * NBDN + ((size_t)(b * DM + d)) * DS + nq * 4);
    float h0 = hv.x, h1 = hv.y, h2 = hv.z, h3 = hv.w;

    const uint32_t* dxp = dx + ((size_t)(b * L_SEQ + l0)) * DM + d;
    const float*    bp  = xdbl + ((size_t)(b * L_SEQ + l0)) * 64 + DR + nq * 4;
    float* op = out + ((size_t)(b * L_SEQ + l0)) * DM + d;

    #pragma unroll 4
    for (int i = 0; i < CL; ++i) {
        uint32_t v = dxp[(size_t)i * DM];
        float dt = __uint_as_float(v & 0xFFFF0000u);
        float xv = __uint_as_float(v << 16);
        float4 B4 = *(const float4*)(bp + (size_t)i * 64);
        float4 C4 = *(const float4*)(bp + (size_t)i * 64 + DS);
        float u = dt * xv;
        float dA;
        dA = exp2f(dt * a2.x); h0 = fmaf(dA, h0, u * B4.x);
        dA = exp2f(dt * a2.y); h1 = fmaf(dA, h1, u * B4.y);
        dA = exp2f(dt * a2.z); h2 = fmaf(dA, h2, u * B4.z);
        dA = exp2f(dt * a2.w); h3 = fmaf(dA, h3, u * B4.w);
        float p = fmaf(h3, C4.w, fmaf(h2, C4.z, fmaf(h1, C4.y, h0 * C4.x)));
        p += __shfl_xor(p, 16);
        p += __shfl_xor(p, 32);
        if (nq == 0) op[(size_t)i * DM] = fmaf(xv, Dv, p);
    }
}

extern "C" void kernel_launch(void* const* d_in, const int* in_sizes, int n_in,
                              void* d_out, int out_size, void* d_ws, size_t ws_size,
                              hipStream_t stream) {
    const float* x      = (const float*)d_in[0];
    const float* A_log  = (const float*)d_in[1];
    const float* Dvec   = (const float*)d_in[2];
    const float* Wx     = (const float*)d_in[3];
    const float* Wdt    = (const float*)d_in[4];
    const float* dtb    = (const float*)d_in[5];
    const float* convw  = (const float*)d_in[6];
    const float* convb  = (const float*)d_in[7];
    float* out = (float*)d_out;
    float* wsf = (float*)d_ws;

    uint32_t* dx    = (uint32_t*)(wsf + WS_DX);
    float*    xdbl  = wsf + WS_XDBL;
    float*    WxT   = wsf + WS_WXT;
    float*    WdtT  = wsf + WS_WDTT;
    float*    A2    = wsf + WS_A2;
    float*    dtsum = wsf + WS_DTSUM;
    float*    S     = wsf + WS_S;

    k_prep<<<128, 256, 0, stream>>>(Wx, Wdt, A_log, WxT, WdtT, A2);
    k_front<<<1024, 256, 0, stream>>>(x, convw, convb, WxT, WdtT, dtb, dx, xdbl);
    k_scan1<<<dim3(512, 4), 256, 0, stream>>>(dx, xdbl, A2, S, dtsum);
    k_scan2<<<128, 256, 0, stream>>>(dtsum, A2, S);
    k_scan3<<<dim3(512, 4), 256, 0, stream>>>(dx, xdbl, A2, Dvec, S, out);
}